// Round 6
// baseline (239.566 us; speedup 1.0000x reference)
//
#include <hip/hip_runtime.h>

// DecoderCBatchNorm, round 6: identical to round 5 EXCEPT the MLP kernel gets
// __launch_bounds__(256, 1) -> VGPR cap 512 instead of ~92/128.
// Unified theory of rounds 1-5: every thread-per-point MLP spilled its
// cf[32]+net[32]+h[32](+wa/wb) register arrays to scratch (round-1 smoking
// gun: VGPR_Count=92 < 96 floats of live state). Spilled accumulators inside
// the unrolled MAC loop = scratch load+store per touch at ~1 wave/SIMD = the
// shared ~70us wall. This round removes the spill while keeping the
// readlane weight path (no scalar-drain, no DS-pipe traffic, no per-MAC mem).
// B=16, T=4096, L=4, H=W=128, D=32. Output [B,T] f32.

#define LL 4
#define HH 128
#define WW 128
#define DD 32
#define NPT 65536

__device__ __forceinline__ float bcast(float v, int srclane) {
    return __int_as_float(__builtin_amdgcn_readlane(__float_as_int(v), srclane));
}

// ---------------------------------------------------------------- gather ----
__global__ __launch_bounds__(256) void gather_kernel(
    const float* __restrict__ p,        // [B,T,3]
    const float* __restrict__ c,        // [B,L,H,W,D]
    const float* __restrict__ Cmat,     // [B,L,4,3]
    float4* __restrict__ cf_ws)         // [B*T*8] float4
{
    const int tid = blockIdx.x * blockDim.x + threadIdx.x;  // 0..524287
    const int t  = tid >> 3;
    const int dg = tid & 7;
    const int b  = t >> 12;

    const float* pp = p + (size_t)t * 3;
    const float pm0 = pp[0] / 0.55f;
    const float pm1 = pp[1] / 0.55f;
    const float pm2 = pp[2] / 0.55f;

    const float interval = (float)(2.0 / 127.0);

    float4 acc = make_float4(0.f, 0.f, 0.f, 0.f);

    #pragma unroll
    for (int l = 0; l < LL; ++l) {
        const float* cm = Cmat + (size_t)(b * LL + l) * 12;
        const float c00 = cm[0], c01 = cm[1], c02 = cm[2];
        const float c10 = cm[3], c11 = cm[4], c12 = cm[5];
        const float c30 = cm[9];

        float pr0 = c00 * pm0 + c01 * pm1 + c02 * pm2;
        float pr1 = c10 * pm0 + c11 * pm1 + c12 * pm2;
        const float denom = c30 + 0.05f;
        pr0 = pr0 / denom;
        pr1 = pr1 / denom;

        float xg = (pr0 + 1.0f) / interval;
        float yg = (pr1 + 1.0f) / interval;
        xg = (xg >= 127.0f) ? 126.9f : xg;
        xg = (xg < 0.0f)    ? 0.0f   : xg;
        yg = (yg >= 127.0f) ? 126.9f : yg;
        yg = (yg < 0.0f)    ? 0.0f   : yg;

        const float xl = rintf(xg - 0.5f);
        const float xr = rintf(xg + 0.5f);
        const float yl = rintf(yg - 0.5f);
        const float yh = rintf(yg + 0.5f);
        const int xil = (int)xl, xir = (int)xr, yil = (int)yl, yih = (int)yh;

        const float dx = xr - xg;
        const float dy = yh - yg;
        const float w11 = dx * dy;
        const float w12 = (1.0f - dx) * dy;
        const float w21 = dx * (1.0f - dy);
        const float w22 = (1.0f - dx) * (1.0f - dy);

        const float* plane = c + (size_t)(b * LL + l) * (HH * WW * DD);
        const int doff = dg * 4;
        const float4 a  = *(const float4*)(plane + ((size_t)xil * WW + yil) * DD + doff);
        const float4 e  = *(const float4*)(plane + ((size_t)xir * WW + yil) * DD + doff);
        const float4 g  = *(const float4*)(plane + ((size_t)xil * WW + yih) * DD + doff);
        const float4 d4 = *(const float4*)(plane + ((size_t)xir * WW + yih) * DD + doff);

        acc.x += w11 * a.x + w12 * e.x + w21 * g.x + w22 * d4.x;
        acc.y += w11 * a.y + w12 * e.y + w21 * g.y + w22 * d4.y;
        acc.z += w11 * a.z + w12 * e.z + w21 * g.z + w22 * d4.z;
        acc.w += w11 * a.w + w12 * e.w + w21 * g.w + w22 * d4.w;
    }

    cf_ws[tid] = acc;   // coalesced: 64 lanes x 16 B contiguous
}

// ------------------------------------------------------------------- MLP ----
// __launch_bounds__(256, 1): min 1 wave/EU -> VGPR cap 512. The ~200 floats
// of live state (cf, net, h, r0, wa, wb) now fit in registers -> no spill.
__global__ __launch_bounds__(256, 1) void mlp_kernel(
    const float* __restrict__ p,        // [B,T,3]
    const float* __restrict__ cf_ws,    // [B*T,32]
    const float* __restrict__ fc_p_W,   // [3,D]
    const float* __restrict__ fc_p_b,   // [D]
    const float* __restrict__ W0,       // [5,D,D]
    const float* __restrict__ b0,       // [5,D]
    const float* __restrict__ W1,       // [5,D,D]
    const float* __restrict__ b1,       // [5,D]
    const float* __restrict__ fc_out_W, // [D]
    const float* __restrict__ fc_out_b, // [1]
    float* __restrict__ out)            // [B,T]
{
    const int t    = blockIdx.x * blockDim.x + threadIdx.x;
    const int lane = threadIdx.x & 63;
    const int j32  = lane & 31;

    const float* pp = p + (size_t)t * 3;
    const float px = pp[0], py = pp[1], pz = pp[2];

    float cf[DD];
    const float4* cfv = (const float4*)(cf_ws + (size_t)t * DD);
    #pragma unroll
    for (int q = 0; q < DD / 4; ++q) {
        const float4 v = cfv[q];
        cf[4*q+0] = v.x; cf[4*q+1] = v.y; cf[4*q+2] = v.z; cf[4*q+3] = v.w;
    }

    // fc_p: per-lane load + readlane broadcast (off the scalar-drain path)
    const float vpb  = fc_p_b[j32];
    const float vpw0 = fc_p_W[j32];
    const float vpw1 = fc_p_W[DD + j32];
    const float vpw2 = fc_p_W[2 * DD + j32];

    float net[DD];
    #pragma unroll
    for (int j = 0; j < DD; ++j) {
        net[j] = bcast(vpb, j) + px * bcast(vpw0, j) + py * bcast(vpw1, j)
               + pz * bcast(vpw2, j) + cf[j];
    }

    float h[DD];
    for (int s = 0; s < 5; ++s) {
        // stage weights -> VGPRs, coalesced (lane L holds flat elem r*64+L)
        const float* Ws0 = W0 + (size_t)s * DD * DD;
        const float* Ws1 = W1 + (size_t)s * DD * DD;
        float wa[16], wb[16];
        #pragma unroll
        for (int r = 0; r < 16; ++r) wa[r] = Ws0[r * 64 + lane];
        #pragma unroll
        for (int r = 0; r < 16; ++r) wb[r] = Ws1[r * 64 + lane];
        const float vb0 = b0[s * DD + j32];
        const float vb1 = b1[s * DD + j32];

        if (s > 0) {
            #pragma unroll
            for (int j = 0; j < DD; ++j) net[j] += cf[j];
        }

        // ---- h = b0 + relu(net) @ W0 ----
        float r0[DD];
        #pragma unroll
        for (int j = 0; j < DD; ++j) r0[j] = fmaxf(net[j], 0.0f);
        #pragma unroll
        for (int j = 0; j < DD; ++j) h[j] = bcast(vb0, j);
        #pragma unroll
        for (int k = 0; k < DD; ++k) {
            const float xk = r0[k];
            #pragma unroll
            for (int j = 0; j < DD; ++j) {
                const int f = k * DD + j;
                h[j] += xk * bcast(wa[f >> 6], f & 63);
            }
        }

        // ---- net += b1 + relu(h) @ W1 ----
        #pragma unroll
        for (int j = 0; j < DD; ++j) net[j] += bcast(vb1, j);
        #pragma unroll
        for (int j = 0; j < DD; ++j) r0[j] = fmaxf(h[j], 0.0f);
        #pragma unroll
        for (int k = 0; k < DD; ++k) {
            const float xk = r0[k];
            #pragma unroll
            for (int j = 0; j < DD; ++j) {
                const int f = k * DD + j;
                net[j] += xk * bcast(wb[f >> 6], f & 63);
            }
        }
    }

    // fc_out
    const float vwo = fc_out_W[j32];
    float o = fc_out_b[0];
    #pragma unroll
    for (int k = 0; k < DD; ++k) o += fmaxf(net[k], 0.0f) * bcast(vwo, k);
    out[t] = o;
}

// ------------------------------------------------- round-1 fused fallback ---
__global__ __launch_bounds__(256, 1) void decoder_fused_kernel(
    const float* __restrict__ p,
    const float* __restrict__ c,
    const float* __restrict__ Cmat,
    const float* __restrict__ fc_p_W,
    const float* __restrict__ fc_p_b,
    const float* __restrict__ W0,
    const float* __restrict__ b0,
    const float* __restrict__ W1,
    const float* __restrict__ b1,
    const float* __restrict__ fc_out_W,
    const float* __restrict__ fc_out_b,
    float* __restrict__ out)
{
    const int t = blockIdx.x * blockDim.x + threadIdx.x;
    const int b = t >> 12;

    const float* pp = p + (size_t)t * 3;
    const float px = pp[0], py = pp[1], pz = pp[2];
    const float pm0 = px / 0.55f, pm1 = py / 0.55f, pm2 = pz / 0.55f;

    float cf[DD];
    #pragma unroll
    for (int j = 0; j < DD; ++j) cf[j] = 0.0f;
    const float interval = (float)(2.0 / 127.0);

    #pragma unroll
    for (int l = 0; l < LL; ++l) {
        const float* cm = Cmat + (size_t)(b * LL + l) * 12;
        float pr0 = cm[0]*pm0 + cm[1]*pm1 + cm[2]*pm2;
        float pr1 = cm[3]*pm0 + cm[4]*pm1 + cm[5]*pm2;
        const float denom = cm[9] + 0.05f;
        pr0 /= denom; pr1 /= denom;
        float xg = (pr0 + 1.0f) / interval;
        float yg = (pr1 + 1.0f) / interval;
        xg = (xg >= 127.0f) ? 126.9f : xg; xg = (xg < 0.0f) ? 0.0f : xg;
        yg = (yg >= 127.0f) ? 126.9f : yg; yg = (yg < 0.0f) ? 0.0f : yg;
        const float xl = rintf(xg - 0.5f), xr = rintf(xg + 0.5f);
        const float yl = rintf(yg - 0.5f), yh = rintf(yg + 0.5f);
        const int xil = (int)xl, xir = (int)xr, yil = (int)yl, yih = (int)yh;
        const float dx = xr - xg, dy = yh - yg;
        const float w11 = dx*dy, w12 = (1.f-dx)*dy, w21 = dx*(1.f-dy), w22 = (1.f-dx)*(1.f-dy);
        const float* plane = c + (size_t)(b * LL + l) * (HH * WW * DD);
        const float4* f11 = (const float4*)(plane + ((size_t)xil * WW + yil) * DD);
        const float4* f12 = (const float4*)(plane + ((size_t)xir * WW + yil) * DD);
        const float4* f21 = (const float4*)(plane + ((size_t)xil * WW + yih) * DD);
        const float4* f22 = (const float4*)(plane + ((size_t)xir * WW + yih) * DD);
        #pragma unroll
        for (int q = 0; q < DD / 4; ++q) {
            const float4 a = f11[q], e = f12[q], g = f21[q], d4 = f22[q];
            cf[4*q+0] += w11*a.x + w12*e.x + w21*g.x + w22*d4.x;
            cf[4*q+1] += w11*a.y + w12*e.y + w21*g.y + w22*d4.y;
            cf[4*q+2] += w11*a.z + w12*e.z + w21*g.z + w22*d4.z;
            cf[4*q+3] += w11*a.w + w12*e.w + w21*g.w + w22*d4.w;
        }
    }

    float net[DD];
    #pragma unroll
    for (int j = 0; j < DD; ++j)
        net[j] = fc_p_b[j] + px*fc_p_W[j] + py*fc_p_W[DD+j] + pz*fc_p_W[2*DD+j] + cf[j];

    for (int s = 0; s < 5; ++s) {
        if (s > 0) {
            #pragma unroll
            for (int j = 0; j < DD; ++j) net[j] += cf[j];
        }
        const float* w0 = W0 + (size_t)s * DD * DD;
        const float* w1 = W1 + (size_t)s * DD * DD;
        float h[DD];
        #pragma unroll
        for (int j = 0; j < DD; ++j) h[j] = b0[s * DD + j];
        #pragma unroll 4
        for (int k = 0; k < DD; ++k) {
            const float xk = fmaxf(net[k], 0.0f);
            #pragma unroll
            for (int j = 0; j < DD; ++j) h[j] += xk * w0[k * DD + j];
        }
        #pragma unroll
        for (int j = 0; j < DD; ++j) net[j] += b1[s * DD + j];
        #pragma unroll 4
        for (int k = 0; k < DD; ++k) {
            const float hk = fmaxf(h[k], 0.0f);
            #pragma unroll
            for (int j = 0; j < DD; ++j) net[j] += hk * w1[k * DD + j];
        }
    }

    float o = fc_out_b[0];
    #pragma unroll
    for (int k = 0; k < DD; ++k) o += fmaxf(net[k], 0.0f) * fc_out_W[k];
    out[t] = o;
}

extern "C" void kernel_launch(void* const* d_in, const int* in_sizes, int n_in,
                              void* d_out, int out_size, void* d_ws, size_t ws_size,
                              hipStream_t stream) {
    const float* p        = (const float*)d_in[0];
    // d_in[1] = z  [B,128]  -- unused by the reference
    const float* c        = (const float*)d_in[2];
    const float* Cmat     = (const float*)d_in[3];
    const float* fc_p_W   = (const float*)d_in[4];
    const float* fc_p_b   = (const float*)d_in[5];
    const float* W0       = (const float*)d_in[6];
    const float* b0       = (const float*)d_in[7];
    const float* W1       = (const float*)d_in[8];
    const float* b1       = (const float*)d_in[9];
    const float* fc_out_W = (const float*)d_in[10];
    const float* fc_out_b = (const float*)d_in[11];
    float* out = (float*)d_out;

    const size_t cf_bytes = (size_t)NPT * DD * 4;   // 8 MiB

    if (ws_size >= cf_bytes) {
        float* cf_ws = (float*)d_ws;
        gather_kernel<<<(NPT * 8) / 256, 256, 0, stream>>>(p, c, Cmat, (float4*)cf_ws);
        mlp_kernel<<<NPT / 256, 256, 0, stream>>>(p, cf_ws, fc_p_W, fc_p_b,
                                                  W0, b0, W1, b1, fc_out_W, fc_out_b, out);
    } else {
        decoder_fused_kernel<<<NPT / 256, 256, 0, stream>>>(p, c, Cmat, fc_p_W, fc_p_b,
                                                            W0, b0, W1, b1, fc_out_W, fc_out_b, out);
    }
}

// Round 7
// 211.881 us; speedup vs baseline: 1.1307x; 1.1307x over previous
//
#include <hip/hip_runtime.h>
#include <hip/hip_bf16.h>

// DecoderCBatchNorm, round 7: MFMA MLP.
// Gather: unchanged (round-2 verified, 8 thr/pt, coalesced).
// MLP: wave = 16 points. Each 32x32 matmul = 2x mfma_f32_16x16x32_bf16
// (K=32 == dot length). net/residual kept in f32 C-layout regs; only MFMA
// operands rounded to bf16 (f32 accumulation). Bias injected via C operand.
// Layer transpose (C-layout -> A-layout) via wave-private LDS.
// All 10 matmuls' B-fragments preloaded to VGPRs -> zero global traffic in loop.
// Layouts (HW-verified per guide m89/m118-m122):
//   A: lane holds m=lane&15, k=(lane>>4)*8 + j   (8 bf16 / 4 VGPRs)
//   C/D: col(n)=lane&15, row(m)=(lane>>4)*4 + reg
// B=16, T=4096, L=4, H=W=128, D=32. Output [B,T] f32.

#define LL 4
#define HH 128
#define WW 128
#define DD 32
#define NPT 65536

typedef __attribute__((ext_vector_type(8))) short bf16x8t;
typedef __attribute__((ext_vector_type(4))) float f32x4;

union ABfrag { bf16x8t v; unsigned u[4]; };

__device__ __forceinline__ unsigned pk2(float a, float b) {
    __hip_bfloat16 ha = __float2bfloat16(a);   // RNE
    __hip_bfloat16 hb = __float2bfloat16(b);
    unsigned short ua = *reinterpret_cast<unsigned short*>(&ha);
    unsigned short ub = *reinterpret_cast<unsigned short*>(&hb);
    return (unsigned)ua | ((unsigned)ub << 16);
}

// ---------------------------------------------------------------- gather ----
__global__ __launch_bounds__(256) void gather_kernel(
    const float* __restrict__ p,
    const float* __restrict__ c,
    const float* __restrict__ Cmat,
    float4* __restrict__ cf_ws)
{
    const int tid = blockIdx.x * blockDim.x + threadIdx.x;
    const int t  = tid >> 3;
    const int dg = tid & 7;
    const int b  = t >> 12;

    const float* pp = p + (size_t)t * 3;
    const float pm0 = pp[0] / 0.55f;
    const float pm1 = pp[1] / 0.55f;
    const float pm2 = pp[2] / 0.55f;

    const float interval = (float)(2.0 / 127.0);
    float4 acc = make_float4(0.f, 0.f, 0.f, 0.f);

    #pragma unroll
    for (int l = 0; l < LL; ++l) {
        const float* cm = Cmat + (size_t)(b * LL + l) * 12;
        const float c00 = cm[0], c01 = cm[1], c02 = cm[2];
        const float c10 = cm[3], c11 = cm[4], c12 = cm[5];
        const float c30 = cm[9];

        float pr0 = c00 * pm0 + c01 * pm1 + c02 * pm2;
        float pr1 = c10 * pm0 + c11 * pm1 + c12 * pm2;
        const float denom = c30 + 0.05f;
        pr0 = pr0 / denom;
        pr1 = pr1 / denom;

        float xg = (pr0 + 1.0f) / interval;
        float yg = (pr1 + 1.0f) / interval;
        xg = (xg >= 127.0f) ? 126.9f : xg;
        xg = (xg < 0.0f)    ? 0.0f   : xg;
        yg = (yg >= 127.0f) ? 126.9f : yg;
        yg = (yg < 0.0f)    ? 0.0f   : yg;

        const float xl = rintf(xg - 0.5f);
        const float xr = rintf(xg + 0.5f);
        const float yl = rintf(yg - 0.5f);
        const float yh = rintf(yg + 0.5f);
        const int xil = (int)xl, xir = (int)xr, yil = (int)yl, yih = (int)yh;

        const float dx = xr - xg;
        const float dy = yh - yg;
        const float w11 = dx * dy;
        const float w12 = (1.0f - dx) * dy;
        const float w21 = dx * (1.0f - dy);
        const float w22 = (1.0f - dx) * (1.0f - dy);

        const float* plane = c + (size_t)(b * LL + l) * (HH * WW * DD);
        const int doff = dg * 4;
        const float4 a  = *(const float4*)(plane + ((size_t)xil * WW + yil) * DD + doff);
        const float4 e  = *(const float4*)(plane + ((size_t)xir * WW + yil) * DD + doff);
        const float4 g  = *(const float4*)(plane + ((size_t)xil * WW + yih) * DD + doff);
        const float4 d4 = *(const float4*)(plane + ((size_t)xir * WW + yih) * DD + doff);

        acc.x += w11 * a.x + w12 * e.x + w21 * g.x + w22 * d4.x;
        acc.y += w11 * a.y + w12 * e.y + w21 * g.y + w22 * d4.y;
        acc.z += w11 * a.z + w12 * e.z + w21 * g.z + w22 * d4.z;
        acc.w += w11 * a.w + w12 * e.w + w21 * g.w + w22 * d4.w;
    }

    cf_ws[tid] = acc;
}

// -------------------------------------------------------------- MFMA MLP ----
__global__ __launch_bounds__(256) void mlp_mfma_kernel(
    const float* __restrict__ p,        // [B,T,3]
    const float* __restrict__ cf_ws,    // [B*T,32]
    const float* __restrict__ fc_p_W,   // [3,32]
    const float* __restrict__ fc_p_b,   // [32]
    const float* __restrict__ W0,       // [5,32,32]
    const float* __restrict__ b0,       // [5,32]
    const float* __restrict__ W1,       // [5,32,32]
    const float* __restrict__ b1,       // [5,32]
    const float* __restrict__ fc_out_W, // [32]
    const float* __restrict__ fc_out_b, // [1]
    float* __restrict__ out)            // [B,T]
{
    __shared__ float xb[4][16][36];     // per-wave 16pt x 32ch (+pad) staging

    const int lane = threadIdx.x & 63;
    const int wv   = threadIdx.x >> 6;            // wave in block, 0..3
    const int cch  = lane & 15;                   // n / channel-in-tile
    const int q    = lane >> 4;                   // quad, 0..3
    const int tpt  = (blockIdx.x * 4 + wv) * 16;  // first point of this wave

    float (*myxb)[36] = xb[wv];

    // ---- preload all B-fragments (bf16-packed weights) into VGPRs ----
    // B frag for tile nb: element j holds W[k=8q+j][nb*16 + cch]
    unsigned wB[5][2][2][4];   // [stage][W0/W1][tile][u-reg]
    #pragma unroll
    for (int s = 0; s < 5; ++s) {
        #pragma unroll
        for (int m = 0; m < 2; ++m) {
            const float* Wm = (m ? W1 : W0) + s * DD * DD;
            #pragma unroll
            for (int tile = 0; tile < 2; ++tile) {
                const float* base = Wm + tile * 16 + cch;
                #pragma unroll
                for (int i = 0; i < 4; ++i) {
                    const float wlo = base[(8 * q + 2 * i)     * DD];
                    const float whi = base[(8 * q + 2 * i + 1) * DD];
                    wB[s][m][tile][i] = pk2(wlo, whi);
                }
            }
        }
    }
    // biases in C-layout (per-lane: channel cch and cch+16)
    float bc0[5][2], bc1[5][2];
    #pragma unroll
    for (int s = 0; s < 5; ++s) {
        bc0[s][0] = b0[s * DD + cch];
        bc0[s][1] = b0[s * DD + 16 + cch];
        bc1[s][0] = b1[s * DD + cch];
        bc1[s][1] = b1[s * DD + 16 + cch];
    }
    const float fpb0 = fc_p_b[cch],      fpb1 = fc_p_b[16 + cch];
    const float fw00 = fc_p_W[cch],      fw01 = fc_p_W[16 + cch];
    const float fw10 = fc_p_W[DD + cch], fw11 = fc_p_W[DD + 16 + cch];
    const float fw20 = fc_p_W[2*DD + cch], fw21 = fc_p_W[2*DD + 16 + cch];

    // ---- initial net = fc_p(p) + cf, in C-layout (row = 4q+r, col = cch) ----
    f32x4 net0, net1, cf0, cf1;
    #pragma unroll
    for (int r = 0; r < 4; ++r) {
        const int pt = tpt + q * 4 + r;
        cf0[r] = cf_ws[(size_t)pt * DD + cch];
        cf1[r] = cf_ws[(size_t)pt * DD + 16 + cch];
        const float* pp = p + (size_t)pt * 3;
        const float px = pp[0], py = pp[1], pz = pp[2];
        net0[r] = fpb0 + px * fw00 + py * fw10 + pz * fw20 + cf0[r];
        net1[r] = fpb1 + px * fw01 + py * fw11 + pz * fw21 + cf1[r];
    }

    // ---- 5 resnet blocks ----
    #pragma unroll
    for (int s = 0; s < 5; ++s) {
        if (s > 0) {
            #pragma unroll
            for (int r = 0; r < 4; ++r) { net0[r] += cf0[r]; net1[r] += cf1[r]; }
        }

        // transpose relu(net): C-layout -> LDS [pt][ch]
        #pragma unroll
        for (int r = 0; r < 4; ++r) {
            myxb[q * 4 + r][cch]      = fmaxf(net0[r], 0.0f);
            myxb[q * 4 + r][16 + cch] = fmaxf(net1[r], 0.0f);
        }
        __syncthreads();
        ABfrag A1;
        {
            const float* row = myxb[cch] + 8 * q;       // pt = cch, k = 8q..
            const f32x4 alo = *(const f32x4*)(row);
            const f32x4 ahi = *(const f32x4*)(row + 4);
            A1.u[0] = pk2(alo[0], alo[1]);
            A1.u[1] = pk2(alo[2], alo[3]);
            A1.u[2] = pk2(ahi[0], ahi[1]);
            A1.u[3] = pk2(ahi[2], ahi[3]);
        }
        __syncthreads();

        // h = relu(net) @ W0 + b0   (bias via C operand)
        f32x4 h0 = { bc0[s][0], bc0[s][0], bc0[s][0], bc0[s][0] };
        f32x4 h1 = { bc0[s][1], bc0[s][1], bc0[s][1], bc0[s][1] };
        {
            ABfrag B0a, B0b;
            #pragma unroll
            for (int i = 0; i < 4; ++i) { B0a.u[i] = wB[s][0][0][i]; B0b.u[i] = wB[s][0][1][i]; }
            h0 = __builtin_amdgcn_mfma_f32_16x16x32_bf16(A1.v, B0a.v, h0, 0, 0, 0);
            h1 = __builtin_amdgcn_mfma_f32_16x16x32_bf16(A1.v, B0b.v, h1, 0, 0, 0);
        }

        // transpose relu(h)
        #pragma unroll
        for (int r = 0; r < 4; ++r) {
            myxb[q * 4 + r][cch]      = fmaxf(h0[r], 0.0f);
            myxb[q * 4 + r][16 + cch] = fmaxf(h1[r], 0.0f);
        }
        __syncthreads();
        ABfrag A2;
        {
            const float* row = myxb[cch] + 8 * q;
            const f32x4 alo = *(const f32x4*)(row);
            const f32x4 ahi = *(const f32x4*)(row + 4);
            A2.u[0] = pk2(alo[0], alo[1]);
            A2.u[1] = pk2(alo[2], alo[3]);
            A2.u[2] = pk2(ahi[0], ahi[1]);
            A2.u[3] = pk2(ahi[2], ahi[3]);
        }
        __syncthreads();

        // net = (net + b1) + relu(h) @ W1   (residual via C operand)
        #pragma unroll
        for (int r = 0; r < 4; ++r) { net0[r] += bc1[s][0]; net1[r] += bc1[s][1]; }
        {
            ABfrag B1a, B1b;
            #pragma unroll
            for (int i = 0; i < 4; ++i) { B1a.u[i] = wB[s][1][0][i]; B1b.u[i] = wB[s][1][1][i]; }
            net0 = __builtin_amdgcn_mfma_f32_16x16x32_bf16(A2.v, B1a.v, net0, 0, 0, 0);
            net1 = __builtin_amdgcn_mfma_f32_16x16x32_bf16(A2.v, B1b.v, net1, 0, 0, 0);
        }
    }

    // ---- fc_out: per-point dot over 32 channels (f32, exact) ----
    const float wo0 = fc_out_W[cch];
    const float wo1 = fc_out_W[16 + cch];
    float acc[4];
    #pragma unroll
    for (int r = 0; r < 4; ++r)
        acc[r] = fmaxf(net0[r], 0.0f) * wo0 + fmaxf(net1[r], 0.0f) * wo1;
    #pragma unroll
    for (int m = 1; m < 16; m <<= 1) {
        #pragma unroll
        for (int r = 0; r < 4; ++r) acc[r] += __shfl_xor(acc[r], m, 64);
    }
    if (cch == 0) {
        const float ob = fc_out_b[0];
        #pragma unroll
        for (int r = 0; r < 4; ++r) out[tpt + q * 4 + r] = acc[r] + ob;
    }
}

// ------------------------------------------------- round-1 fused fallback ---
__global__ __launch_bounds__(256) void decoder_fused_kernel(
    const float* __restrict__ p,
    const float* __restrict__ c,
    const float* __restrict__ Cmat,
    const float* __restrict__ fc_p_W,
    const float* __restrict__ fc_p_b,
    const float* __restrict__ W0,
    const float* __restrict__ b0,
    const float* __restrict__ W1,
    const float* __restrict__ b1,
    const float* __restrict__ fc_out_W,
    const float* __restrict__ fc_out_b,
    float* __restrict__ out)
{
    const int t = blockIdx.x * blockDim.x + threadIdx.x;
    const int b = t >> 12;

    const float* pp = p + (size_t)t * 3;
    const float px = pp[0], py = pp[1], pz = pp[2];
    const float pm0 = px / 0.55f, pm1 = py / 0.55f, pm2 = pz / 0.55f;

    float cf[DD];
    #pragma unroll
    for (int j = 0; j < DD; ++j) cf[j] = 0.0f;
    const float interval = (float)(2.0 / 127.0);

    #pragma unroll
    for (int l = 0; l < LL; ++l) {
        const float* cm = Cmat + (size_t)(b * LL + l) * 12;
        float pr0 = cm[0]*pm0 + cm[1]*pm1 + cm[2]*pm2;
        float pr1 = cm[3]*pm0 + cm[4]*pm1 + cm[5]*pm2;
        const float denom = cm[9] + 0.05f;
        pr0 /= denom; pr1 /= denom;
        float xg = (pr0 + 1.0f) / interval;
        float yg = (pr1 + 1.0f) / interval;
        xg = (xg >= 127.0f) ? 126.9f : xg; xg = (xg < 0.0f) ? 0.0f : xg;
        yg = (yg >= 127.0f) ? 126.9f : yg; yg = (yg < 0.0f) ? 0.0f : yg;
        const float xl = rintf(xg - 0.5f), xr = rintf(xg + 0.5f);
        const float yl = rintf(yg - 0.5f), yh = rintf(yg + 0.5f);
        const int xil = (int)xl, xir = (int)xr, yil = (int)yl, yih = (int)yh;
        const float dx = xr - xg, dy = yh - yg;
        const float w11 = dx*dy, w12 = (1.f-dx)*dy, w21 = dx*(1.f-dy), w22 = (1.f-dx)*(1.f-dy);
        const float* plane = c + (size_t)(b * LL + l) * (HH * WW * DD);
        const float4* f11 = (const float4*)(plane + ((size_t)xil * WW + yil) * DD);
        const float4* f12 = (const float4*)(plane + ((size_t)xir * WW + yil) * DD);
        const float4* f21 = (const float4*)(plane + ((size_t)xil * WW + yih) * DD);
        const float4* f22 = (const float4*)(plane + ((size_t)xir * WW + yih) * DD);
        #pragma unroll
        for (int qq = 0; qq < DD / 4; ++qq) {
            const float4 a = f11[qq], e = f12[qq], g = f21[qq], d4 = f22[qq];
            cf[4*qq+0] += w11*a.x + w12*e.x + w21*g.x + w22*d4.x;
            cf[4*qq+1] += w11*a.y + w12*e.y + w21*g.y + w22*d4.y;
            cf[4*qq+2] += w11*a.z + w12*e.z + w21*g.z + w22*d4.z;
            cf[4*qq+3] += w11*a.w + w12*e.w + w21*g.w + w22*d4.w;
        }
    }

    float net[DD];
    #pragma unroll
    for (int j = 0; j < DD; ++j)
        net[j] = fc_p_b[j] + px*fc_p_W[j] + py*fc_p_W[DD+j] + pz*fc_p_W[2*DD+j] + cf[j];

    for (int s = 0; s < 5; ++s) {
        if (s > 0) {
            #pragma unroll
            for (int j = 0; j < DD; ++j) net[j] += cf[j];
        }
        const float* w0 = W0 + (size_t)s * DD * DD;
        const float* w1 = W1 + (size_t)s * DD * DD;
        float h[DD];
        #pragma unroll
        for (int j = 0; j < DD; ++j) h[j] = b0[s * DD + j];
        #pragma unroll 4
        for (int k = 0; k < DD; ++k) {
            const float xk = fmaxf(net[k], 0.0f);
            #pragma unroll
            for (int j = 0; j < DD; ++j) h[j] += xk * w0[k * DD + j];
        }
        #pragma unroll
        for (int j = 0; j < DD; ++j) net[j] += b1[s * DD + j];
        #pragma unroll 4
        for (int k = 0; k < DD; ++k) {
            const float hk = fmaxf(h[k], 0.0f);
            #pragma unroll
            for (int j = 0; j < DD; ++j) net[j] += hk * w1[k * DD + j];
        }
    }

    float o = fc_out_b[0];
    #pragma unroll
    for (int k = 0; k < DD; ++k) o += fmaxf(net[k], 0.0f) * fc_out_W[k];
    out[t] = o;
}

extern "C" void kernel_launch(void* const* d_in, const int* in_sizes, int n_in,
                              void* d_out, int out_size, void* d_ws, size_t ws_size,
                              hipStream_t stream) {
    const float* p        = (const float*)d_in[0];
    // d_in[1] = z  -- unused by the reference
    const float* c        = (const float*)d_in[2];
    const float* Cmat     = (const float*)d_in[3];
    const float* fc_p_W   = (const float*)d_in[4];
    const float* fc_p_b   = (const float*)d_in[5];
    const float* W0       = (const float*)d_in[6];
    const float* b0       = (const float*)d_in[7];
    const float* W1       = (const float*)d_in[8];
    const float* b1       = (const float*)d_in[9];
    const float* fc_out_W = (const float*)d_in[10];
    const float* fc_out_b = (const float*)d_in[11];
    float* out = (float*)d_out;

    const size_t cf_bytes = (size_t)NPT * DD * 4;   // 8 MiB

    if (ws_size >= cf_bytes) {
        float* cf_ws = (float*)d_ws;
        gather_kernel<<<(NPT * 8) / 256, 256, 0, stream>>>(p, c, Cmat, (float4*)cf_ws);
        // 16 points/wave, 4 waves/block -> 64 points/block -> 1024 blocks
        mlp_mfma_kernel<<<NPT / 64, 256, 0, stream>>>(p, cf_ws, fc_p_W, fc_p_b,
                                                      W0, b0, W1, b1, fc_out_W, fc_out_b, out);
    } else {
        decoder_fused_kernel<<<NPT / 256, 256, 0, stream>>>(p, c, Cmat, fc_p_W, fc_p_b,
                                                            W0, b0, W1, b1, fc_out_W, fc_out_b, out);
    }
}

// Round 8
// 209.701 us; speedup vs baseline: 1.1424x; 1.0104x over previous
//
#include <hip/hip_runtime.h>
#include <hip/hip_bf16.h>

// DecoderCBatchNorm, round 8: single fused kernel (gather + MFMA MLP).
// Timing model resolved: dur_us = ~174us fixed harness reset + 1x kernels.
// Controllable part was ~38us (gather ~30 + mlp ~5 + 2 launches). This round
// fuses to kill the 16 MB cf_ws L2 round-trip, one launch, and double p reads.
// Block = 512 threads = 128 points:
//   Phase 1 (gather): 4 lanes/point x 8 ch; two float4 loads per 128 B texel
//     (fully coalesced); cf -> LDS [128][36] (stride 36: 2-way bank = free).
//   Phase 2 (MLP): 8 waves x 16 pts, round-7 MFMA structure (validated,
//     absmax 0.0625); transpose staging ALIASES the cf buffer (both 4608 f),
//     barrier-separated. Weights loaded per-stage (keeps VGPR lean; stage
//     loop runs once so total convert work is unchanged).
// B=16, T=4096, L=4, H=W=128, D=32. Output [B,T] f32.

#define LL 4
#define HH 128
#define WW 128
#define DD 32
#define NPT 65536

typedef __attribute__((ext_vector_type(8))) short bf16x8t;
typedef __attribute__((ext_vector_type(4))) float f32x4;

union ABfrag { bf16x8t v; unsigned u[4]; };

__device__ __forceinline__ unsigned pk2(float a, float b) {
    __hip_bfloat16 ha = __float2bfloat16(a);   // RNE
    __hip_bfloat16 hb = __float2bfloat16(b);
    unsigned short ua = *reinterpret_cast<unsigned short*>(&ha);
    unsigned short ub = *reinterpret_cast<unsigned short*>(&hb);
    return (unsigned)ua | ((unsigned)ub << 16);
}

__global__ __launch_bounds__(512, 2) void decoder_fused_mfma(
    const float* __restrict__ p,        // [B,T,3]
    const float* __restrict__ c,        // [B,L,H,W,D]
    const float* __restrict__ Cmat,     // [B,L,4,3]
    const float* __restrict__ fc_p_W,   // [3,32]
    const float* __restrict__ fc_p_b,   // [32]
    const float* __restrict__ W0,       // [5,32,32]
    const float* __restrict__ b0,       // [5,32]
    const float* __restrict__ W1,       // [5,32,32]
    const float* __restrict__ b1,       // [5,32]
    const float* __restrict__ fc_out_W, // [32]
    const float* __restrict__ fc_out_b, // [1]
    float* __restrict__ out)            // [B,T]
{
    // Phase 1: cf[pt][ch] at xb[pt*36 + ch]  (128 x 36 = 4608 floats)
    // Phase 2: per-wave 16x36 A-transpose staging, ALIASED (wave wv at +wv*576)
    __shared__ float xb[4608];

    const int tid = threadIdx.x;
    const int b_u = blockIdx.x >> 5;    // batch: 128 pts * 32 blocks = 4096

    // ================================================== phase 1: gather ====
    {
        const int tl = tid >> 2;                    // local point 0..127
        const int dg = tid & 3;                     // channel octet 0..3
        const int t  = blockIdx.x * 128 + tl;

        const float* pp = p + (size_t)t * 3;
        const float pm0 = pp[0] / 0.55f;
        const float pm1 = pp[1] / 0.55f;
        const float pm2 = pp[2] / 0.55f;

        const float interval = (float)(2.0 / 127.0);

        float acc[8];
        #pragma unroll
        for (int i = 0; i < 8; ++i) acc[i] = 0.0f;

        #pragma unroll
        for (int l = 0; l < LL; ++l) {
            const float* cm = Cmat + (size_t)(b_u * LL + l) * 12;
            const float c00 = cm[0], c01 = cm[1], c02 = cm[2];
            const float c10 = cm[3], c11 = cm[4], c12 = cm[5];
            const float c30 = cm[9];

            float pr0 = c00 * pm0 + c01 * pm1 + c02 * pm2;
            float pr1 = c10 * pm0 + c11 * pm1 + c12 * pm2;
            const float denom = c30 + 0.05f;
            pr0 = pr0 / denom;
            pr1 = pr1 / denom;

            float xg = (pr0 + 1.0f) / interval;
            float yg = (pr1 + 1.0f) / interval;
            xg = (xg >= 127.0f) ? 126.9f : xg;
            xg = (xg < 0.0f)    ? 0.0f   : xg;
            yg = (yg >= 127.0f) ? 126.9f : yg;
            yg = (yg < 0.0f)    ? 0.0f   : yg;

            const float xl = rintf(xg - 0.5f);
            const float xr = rintf(xg + 0.5f);
            const float yl = rintf(yg - 0.5f);
            const float yh = rintf(yg + 0.5f);
            const int xil = (int)xl, xir = (int)xr, yil = (int)yl, yih = (int)yh;

            const float dx = xr - xg;
            const float dy = yh - yg;
            const float w11 = dx * dy;
            const float w12 = (1.0f - dx) * dy;
            const float w21 = dx * (1.0f - dy);
            const float w22 = (1.0f - dx) * (1.0f - dy);

            const float* plane = c + (size_t)(b_u * LL + l) * (HH * WW * DD);
            const int doff = dg * 8;
            const float* t11 = plane + ((size_t)xil * WW + yil) * DD + doff;
            const float* t12 = plane + ((size_t)xir * WW + yil) * DD + doff;
            const float* t21 = plane + ((size_t)xil * WW + yih) * DD + doff;
            const float* t22 = plane + ((size_t)xir * WW + yih) * DD + doff;

            #pragma unroll
            for (int hf = 0; hf < 2; ++hf) {
                const float4 a  = *(const float4*)(t11 + 4 * hf);
                const float4 e  = *(const float4*)(t12 + 4 * hf);
                const float4 g  = *(const float4*)(t21 + 4 * hf);
                const float4 d4 = *(const float4*)(t22 + 4 * hf);
                acc[4*hf + 0] += w11 * a.x + w12 * e.x + w21 * g.x + w22 * d4.x;
                acc[4*hf + 1] += w11 * a.y + w12 * e.y + w21 * g.y + w22 * d4.y;
                acc[4*hf + 2] += w11 * a.z + w12 * e.z + w21 * g.z + w22 * d4.z;
                acc[4*hf + 3] += w11 * a.w + w12 * e.w + w21 * g.w + w22 * d4.w;
            }
        }

        float* dst = xb + tl * 36 + dg * 8;
        *(float4*)(dst)     = make_float4(acc[0], acc[1], acc[2], acc[3]);
        *(float4*)(dst + 4) = make_float4(acc[4], acc[5], acc[6], acc[7]);
    }
    __syncthreads();

    // ================================================== phase 2: MFMA MLP ==
    const int lane = tid & 63;
    const int wv   = tid >> 6;              // wave 0..7
    const int cch  = lane & 15;             // channel-in-tile / C col / A row
    const int q    = lane >> 4;             // quad 0..3
    const int tl0  = wv * 16;               // first local point of this wave
    const int tpt  = blockIdx.x * 128 + tl0;

    // cf -> C-layout registers (row = 4q+r, col = cch / cch+16)
    f32x4 cf0, cf1;
    #pragma unroll
    for (int r = 0; r < 4; ++r) {
        const int ptl = tl0 + q * 4 + r;
        cf0[r] = xb[ptl * 36 + cch];
        cf1[r] = xb[ptl * 36 + 16 + cch];
    }

    // fc_p params (per-lane vector loads, L1-hot)
    const float fpb0 = fc_p_b[cch],        fpb1 = fc_p_b[16 + cch];
    const float fw00 = fc_p_W[cch],        fw01 = fc_p_W[16 + cch];
    const float fw10 = fc_p_W[DD + cch],   fw11 = fc_p_W[DD + 16 + cch];
    const float fw20 = fc_p_W[2*DD + cch], fw21 = fc_p_W[2*DD + 16 + cch];

    f32x4 net0, net1;
    #pragma unroll
    for (int r = 0; r < 4; ++r) {
        const int pt = tpt + q * 4 + r;
        const float* pp = p + (size_t)pt * 3;
        const float px = pp[0], py = pp[1], pz = pp[2];
        net0[r] = fpb0 + px * fw00 + py * fw10 + pz * fw20 + cf0[r];
        net1[r] = fpb1 + px * fw01 + py * fw11 + pz * fw21 + cf1[r];
    }

    __syncthreads();   // all cf reads done -> xb can be re-used as staging
    float* myxb = xb + wv * 576;   // 16 rows x 36 (wave-private region)

    #pragma unroll
    for (int s = 0; s < 5; ++s) {
        // stage weights -> bf16 fragments (loads are L1/L2-hot; stage loop
        // runs once, so convert work equals a full preload)
        unsigned wB[2][2][4];   // [W0/W1][tile][u-reg]
        #pragma unroll
        for (int m = 0; m < 2; ++m) {
            const float* Wm = (m ? W1 : W0) + s * DD * DD;
            #pragma unroll
            for (int tile = 0; tile < 2; ++tile) {
                const float* base = Wm + tile * 16 + cch;
                #pragma unroll
                for (int i = 0; i < 4; ++i) {
                    const float wlo = base[(8 * q + 2 * i)     * DD];
                    const float whi = base[(8 * q + 2 * i + 1) * DD];
                    wB[m][tile][i] = pk2(wlo, whi);
                }
            }
        }
        const float bc00 = b0[s * DD + cch];
        const float bc01 = b0[s * DD + 16 + cch];
        const float bc10 = b1[s * DD + cch];
        const float bc11 = b1[s * DD + 16 + cch];

        if (s > 0) {
            #pragma unroll
            for (int r = 0; r < 4; ++r) { net0[r] += cf0[r]; net1[r] += cf1[r]; }
        }

        // transpose relu(net): C-layout -> [pt][ch]
        #pragma unroll
        for (int r = 0; r < 4; ++r) {
            myxb[(q * 4 + r) * 36 + cch]      = fmaxf(net0[r], 0.0f);
            myxb[(q * 4 + r) * 36 + 16 + cch] = fmaxf(net1[r], 0.0f);
        }
        __syncthreads();
        ABfrag A1;
        {
            const float* row = myxb + cch * 36 + 8 * q;   // pt = cch, k = 8q+j
            const f32x4 alo = *(const f32x4*)(row);
            const f32x4 ahi = *(const f32x4*)(row + 4);
            A1.u[0] = pk2(alo[0], alo[1]);
            A1.u[1] = pk2(alo[2], alo[3]);
            A1.u[2] = pk2(ahi[0], ahi[1]);
            A1.u[3] = pk2(ahi[2], ahi[3]);
        }
        __syncthreads();

        // h = relu(net) @ W0 + b0
        f32x4 h0 = { bc00, bc00, bc00, bc00 };
        f32x4 h1 = { bc01, bc01, bc01, bc01 };
        {
            ABfrag B0a, B0b;
            #pragma unroll
            for (int i = 0; i < 4; ++i) { B0a.u[i] = wB[0][0][i]; B0b.u[i] = wB[0][1][i]; }
            h0 = __builtin_amdgcn_mfma_f32_16x16x32_bf16(A1.v, B0a.v, h0, 0, 0, 0);
            h1 = __builtin_amdgcn_mfma_f32_16x16x32_bf16(A1.v, B0b.v, h1, 0, 0, 0);
        }

        // transpose relu(h)
        #pragma unroll
        for (int r = 0; r < 4; ++r) {
            myxb[(q * 4 + r) * 36 + cch]      = fmaxf(h0[r], 0.0f);
            myxb[(q * 4 + r) * 36 + 16 + cch] = fmaxf(h1[r], 0.0f);
        }
        __syncthreads();
        ABfrag A2;
        {
            const float* row = myxb + cch * 36 + 8 * q;
            const f32x4 alo = *(const f32x4*)(row);
            const f32x4 ahi = *(const f32x4*)(row + 4);
            A2.u[0] = pk2(alo[0], alo[1]);
            A2.u[1] = pk2(alo[2], alo[3]);
            A2.u[2] = pk2(ahi[0], ahi[1]);
            A2.u[3] = pk2(ahi[2], ahi[3]);
        }
        __syncthreads();

        // net = (net + b1) + relu(h) @ W1
        #pragma unroll
        for (int r = 0; r < 4; ++r) { net0[r] += bc10; net1[r] += bc11; }
        {
            ABfrag B1a, B1b;
            #pragma unroll
            for (int i = 0; i < 4; ++i) { B1a.u[i] = wB[1][0][i]; B1b.u[i] = wB[1][1][i]; }
            net0 = __builtin_amdgcn_mfma_f32_16x16x32_bf16(A2.v, B1a.v, net0, 0, 0, 0);
            net1 = __builtin_amdgcn_mfma_f32_16x16x32_bf16(A2.v, B1b.v, net1, 0, 0, 0);
        }
    }

    // ---------------------------------------------------------- fc_out -----
    const float wo0 = fc_out_W[cch];
    const float wo1 = fc_out_W[16 + cch];
    float acc[4];
    #pragma unroll
    for (int r = 0; r < 4; ++r)
        acc[r] = fmaxf(net0[r], 0.0f) * wo0 + fmaxf(net1[r], 0.0f) * wo1;
    #pragma unroll
    for (int m = 1; m < 16; m <<= 1) {
        #pragma unroll
        for (int r = 0; r < 4; ++r) acc[r] += __shfl_xor(acc[r], m, 64);
    }
    if (cch == 0) {
        const float ob = fc_out_b[0];
        #pragma unroll
        for (int r = 0; r < 4; ++r) out[tpt + q * 4 + r] = acc[r] + ob;
    }
}

extern "C" void kernel_launch(void* const* d_in, const int* in_sizes, int n_in,
                              void* d_out, int out_size, void* d_ws, size_t ws_size,
                              hipStream_t stream) {
    const float* p        = (const float*)d_in[0];
    // d_in[1] = z  -- unused by the reference
    const float* c        = (const float*)d_in[2];
    const float* Cmat     = (const float*)d_in[3];
    const float* fc_p_W   = (const float*)d_in[4];
    const float* fc_p_b   = (const float*)d_in[5];
    const float* W0       = (const float*)d_in[6];
    const float* b0       = (const float*)d_in[7];
    const float* W1       = (const float*)d_in[8];
    const float* b1       = (const float*)d_in[9];
    const float* fc_out_W = (const float*)d_in[10];
    const float* fc_out_b = (const float*)d_in[11];
    float* out = (float*)d_out;

    // 128 points/block, 512 threads/block -> 512 blocks (2 blocks/CU)
    decoder_fused_mfma<<<NPT / 128, 512, 0, stream>>>(p, c, Cmat, fc_p_W, fc_p_b,
                                                      W0, b0, W1, b1, fc_out_W, fc_out_b, out);
}

// Round 9
// 208.578 us; speedup vs baseline: 1.1486x; 1.0054x over previous
//
#include <hip/hip_runtime.h>
#include <hip/hip_bf16.h>

// DecoderCBatchNorm, round 9: round 8 + XCD-aware batch swizzle + const-div
// strength reduction.
// - Swizzle: batch b's 32 blocks all map to XCD b%8 (blockIdx%8 ~ XCD on
//   gfx950; all 64 blocks/XCD co-resident at 2 blocks/CU) -> the 4 planes
//   (8 MB) of a batch are shared through ONE XCD's L2, converting the ~1.6x
//   texel reuse from LLC-fabric traffic into L2 hits. Gather is path-bound
//   (~4.5 TB/s scattered 128 B granules; same 30 us at 16 and 32 waves/CU),
//   so locality is the only remaining lever.
// - Constant divisions (/0.55, /interval) -> multiplies (<=1 ulp; bilinear
//   blend is continuous across corner-rounding flips, so safe vs 0.275).
//   /denom stays exact IEEE division.
// B=16, T=4096, L=4, H=W=128, D=32. Output [B,T] f32.

#define LL 4
#define HH 128
#define WW 128
#define DD 32
#define NPT 65536

typedef __attribute__((ext_vector_type(8))) short bf16x8t;
typedef __attribute__((ext_vector_type(4))) float f32x4;

union ABfrag { bf16x8t v; unsigned u[4]; };

__device__ __forceinline__ unsigned pk2(float a, float b) {
    __hip_bfloat16 ha = __float2bfloat16(a);   // RNE
    __hip_bfloat16 hb = __float2bfloat16(b);
    unsigned short ua = *reinterpret_cast<unsigned short*>(&ha);
    unsigned short ub = *reinterpret_cast<unsigned short*>(&hb);
    return (unsigned)ua | ((unsigned)ub << 16);
}

__global__ __launch_bounds__(512, 2) void decoder_fused_mfma(
    const float* __restrict__ p,        // [B,T,3]
    const float* __restrict__ c,        // [B,L,H,W,D]
    const float* __restrict__ Cmat,     // [B,L,4,3]
    const float* __restrict__ fc_p_W,   // [3,32]
    const float* __restrict__ fc_p_b,   // [32]
    const float* __restrict__ W0,       // [5,32,32]
    const float* __restrict__ b0,       // [5,32]
    const float* __restrict__ W1,       // [5,32,32]
    const float* __restrict__ b1,       // [5,32]
    const float* __restrict__ fc_out_W, // [32]
    const float* __restrict__ fc_out_b, // [1]
    float* __restrict__ out)            // [B,T]
{
    // Phase 1: cf[pt][ch] at xb[pt*36 + ch]  (128 x 36 = 4608 floats)
    // Phase 2: per-wave 16x36 A-transpose staging, ALIASED (wave wv at +wv*576)
    __shared__ float xb[4608];

    const int tid = threadIdx.x;

    // XCD-aware swizzle: i%8 ~ XCD. batch = (i&7) + 8*(i>>8) in {0..15};
    // block-within-batch = (i>>3)&31. All 32 blocks of a batch share an XCD.
    const int i    = blockIdx.x;                 // 0..511
    const int b_u  = (i & 7) + ((i >> 8) << 3);  // batch
    const int blk  = (i >> 3) & 31;              // block within batch
    const int tbase = b_u * 4096 + blk * 128;    // first point of this block

    const float inv_maxdim   = 1.0f / 0.55f;
    const float inv_interval = 1.0f / (float)(2.0 / 127.0);   // ~63.5

    // ================================================== phase 1: gather ====
    {
        const int tl = tid >> 2;                    // local point 0..127
        const int dg = tid & 3;                     // channel octet 0..3
        const int t  = tbase + tl;

        const float* pp = p + (size_t)t * 3;
        const float pm0 = pp[0] * inv_maxdim;
        const float pm1 = pp[1] * inv_maxdim;
        const float pm2 = pp[2] * inv_maxdim;

        float acc[8];
        #pragma unroll
        for (int ii = 0; ii < 8; ++ii) acc[ii] = 0.0f;

        #pragma unroll
        for (int l = 0; l < LL; ++l) {
            const float* cm = Cmat + (size_t)(b_u * LL + l) * 12;
            const float c00 = cm[0], c01 = cm[1], c02 = cm[2];
            const float c10 = cm[3], c11 = cm[4], c12 = cm[5];
            const float c30 = cm[9];

            float pr0 = c00 * pm0 + c01 * pm1 + c02 * pm2;
            float pr1 = c10 * pm0 + c11 * pm1 + c12 * pm2;
            const float denom = c30 + 0.05f;
            pr0 = pr0 / denom;                       // exact (denom varies)
            pr1 = pr1 / denom;

            float xg = (pr0 + 1.0f) * inv_interval;
            float yg = (pr1 + 1.0f) * inv_interval;
            xg = (xg >= 127.0f) ? 126.9f : xg;
            xg = (xg < 0.0f)    ? 0.0f   : xg;
            yg = (yg >= 127.0f) ? 126.9f : yg;
            yg = (yg < 0.0f)    ? 0.0f   : yg;

            const float xl = rintf(xg - 0.5f);
            const float xr = rintf(xg + 0.5f);
            const float yl = rintf(yg - 0.5f);
            const float yh = rintf(yg + 0.5f);
            const int xil = (int)xl, xir = (int)xr, yil = (int)yl, yih = (int)yh;

            const float dx = xr - xg;
            const float dy = yh - yg;
            const float w11 = dx * dy;
            const float w12 = (1.0f - dx) * dy;
            const float w21 = dx * (1.0f - dy);
            const float w22 = (1.0f - dx) * (1.0f - dy);

            const float* plane = c + (size_t)(b_u * LL + l) * (HH * WW * DD);
            const int doff = dg * 8;
            const float* t11 = plane + ((size_t)xil * WW + yil) * DD + doff;
            const float* t12 = plane + ((size_t)xir * WW + yil) * DD + doff;
            const float* t21 = plane + ((size_t)xil * WW + yih) * DD + doff;
            const float* t22 = plane + ((size_t)xir * WW + yih) * DD + doff;

            #pragma unroll
            for (int hf = 0; hf < 2; ++hf) {
                const float4 a  = *(const float4*)(t11 + 4 * hf);
                const float4 e  = *(const float4*)(t12 + 4 * hf);
                const float4 g  = *(const float4*)(t21 + 4 * hf);
                const float4 d4 = *(const float4*)(t22 + 4 * hf);
                acc[4*hf + 0] += w11 * a.x + w12 * e.x + w21 * g.x + w22 * d4.x;
                acc[4*hf + 1] += w11 * a.y + w12 * e.y + w21 * g.y + w22 * d4.y;
                acc[4*hf + 2] += w11 * a.z + w12 * e.z + w21 * g.z + w22 * d4.z;
                acc[4*hf + 3] += w11 * a.w + w12 * e.w + w21 * g.w + w22 * d4.w;
            }
        }

        float* dst = xb + tl * 36 + dg * 8;
        *(float4*)(dst)     = make_float4(acc[0], acc[1], acc[2], acc[3]);
        *(float4*)(dst + 4) = make_float4(acc[4], acc[5], acc[6], acc[7]);
    }
    __syncthreads();

    // ================================================== phase 2: MFMA MLP ==
    const int lane = tid & 63;
    const int wv   = tid >> 6;              // wave 0..7
    const int cch  = lane & 15;             // channel-in-tile / C col / A row
    const int q    = lane >> 4;             // quad 0..3
    const int tl0  = wv * 16;               // first local point of this wave
    const int tpt  = tbase + tl0;

    // cf -> C-layout registers (row = 4q+r, col = cch / cch+16)
    f32x4 cf0, cf1;
    #pragma unroll
    for (int r = 0; r < 4; ++r) {
        const int ptl = tl0 + q * 4 + r;
        cf0[r] = xb[ptl * 36 + cch];
        cf1[r] = xb[ptl * 36 + 16 + cch];
    }

    // fc_p params (per-lane vector loads, L1-hot)
    const float fpb0 = fc_p_b[cch],        fpb1 = fc_p_b[16 + cch];
    const float fw00 = fc_p_W[cch],        fw01 = fc_p_W[16 + cch];
    const float fw10 = fc_p_W[DD + cch],   fw11 = fc_p_W[DD + 16 + cch];
    const float fw20 = fc_p_W[2*DD + cch], fw21 = fc_p_W[2*DD + 16 + cch];

    f32x4 net0, net1;
    #pragma unroll
    for (int r = 0; r < 4; ++r) {
        const int pt = tpt + q * 4 + r;
        const float* pp = p + (size_t)pt * 3;
        const float px = pp[0], py = pp[1], pz = pp[2];
        net0[r] = fpb0 + px * fw00 + py * fw10 + pz * fw20 + cf0[r];
        net1[r] = fpb1 + px * fw01 + py * fw11 + pz * fw21 + cf1[r];
    }

    __syncthreads();   // all cf reads done -> xb re-used as transpose staging
    float* myxb = xb + wv * 576;   // 16 rows x 36 (wave-private region)

    #pragma unroll
    for (int s = 0; s < 5; ++s) {
        // stage weights -> bf16 fragments (L1/L2-hot loads; loop runs once)
        unsigned wB[2][2][4];   // [W0/W1][tile][u-reg]
        #pragma unroll
        for (int m = 0; m < 2; ++m) {
            const float* Wm = (m ? W1 : W0) + s * DD * DD;
            #pragma unroll
            for (int tile = 0; tile < 2; ++tile) {
                const float* base = Wm + tile * 16 + cch;
                #pragma unroll
                for (int ii = 0; ii < 4; ++ii) {
                    const float wlo = base[(8 * q + 2 * ii)     * DD];
                    const float whi = base[(8 * q + 2 * ii + 1) * DD];
                    wB[m][tile][ii] = pk2(wlo, whi);
                }
            }
        }
        const float bc00 = b0[s * DD + cch];
        const float bc01 = b0[s * DD + 16 + cch];
        const float bc10 = b1[s * DD + cch];
        const float bc11 = b1[s * DD + 16 + cch];

        if (s > 0) {
            #pragma unroll
            for (int r = 0; r < 4; ++r) { net0[r] += cf0[r]; net1[r] += cf1[r]; }
        }

        // transpose relu(net): C-layout -> [pt][ch]
        #pragma unroll
        for (int r = 0; r < 4; ++r) {
            myxb[(q * 4 + r) * 36 + cch]      = fmaxf(net0[r], 0.0f);
            myxb[(q * 4 + r) * 36 + 16 + cch] = fmaxf(net1[r], 0.0f);
        }
        __syncthreads();
        ABfrag A1;
        {
            const float* row = myxb + cch * 36 + 8 * q;   // pt = cch, k = 8q+j
            const f32x4 alo = *(const f32x4*)(row);
            const f32x4 ahi = *(const f32x4*)(row + 4);
            A1.u[0] = pk2(alo[0], alo[1]);
            A1.u[1] = pk2(alo[2], alo[3]);
            A1.u[2] = pk2(ahi[0], ahi[1]);
            A1.u[3] = pk2(ahi[2], ahi[3]);
        }
        __syncthreads();

        // h = relu(net) @ W0 + b0   (bias via C operand)
        f32x4 h0 = { bc00, bc00, bc00, bc00 };
        f32x4 h1 = { bc01, bc01, bc01, bc01 };
        {
            ABfrag B0a, B0b;
            #pragma unroll
            for (int ii = 0; ii < 4; ++ii) { B0a.u[ii] = wB[0][0][ii]; B0b.u[ii] = wB[0][1][ii]; }
            h0 = __builtin_amdgcn_mfma_f32_16x16x32_bf16(A1.v, B0a.v, h0, 0, 0, 0);
            h1 = __builtin_amdgcn_mfma_f32_16x16x32_bf16(A1.v, B0b.v, h1, 0, 0, 0);
        }

        // transpose relu(h)
        #pragma unroll
        for (int r = 0; r < 4; ++r) {
            myxb[(q * 4 + r) * 36 + cch]      = fmaxf(h0[r], 0.0f);
            myxb[(q * 4 + r) * 36 + 16 + cch] = fmaxf(h1[r], 0.0f);
        }
        __syncthreads();
        ABfrag A2;
        {
            const float* row = myxb + cch * 36 + 8 * q;
            const f32x4 alo = *(const f32x4*)(row);
            const f32x4 ahi = *(const f32x4*)(row + 4);
            A2.u[0] = pk2(alo[0], alo[1]);
            A2.u[1] = pk2(alo[2], alo[3]);
            A2.u[2] = pk2(ahi[0], ahi[1]);
            A2.u[3] = pk2(ahi[2], ahi[3]);
        }
        __syncthreads();

        // net = (net + b1) + relu(h) @ W1   (residual via C operand)
        #pragma unroll
        for (int r = 0; r < 4; ++r) { net0[r] += bc10; net1[r] += bc11; }
        {
            ABfrag B1a, B1b;
            #pragma unroll
            for (int ii = 0; ii < 4; ++ii) { B1a.u[ii] = wB[1][0][ii]; B1b.u[ii] = wB[1][1][ii]; }
            net0 = __builtin_amdgcn_mfma_f32_16x16x32_bf16(A2.v, B1a.v, net0, 0, 0, 0);
            net1 = __builtin_amdgcn_mfma_f32_16x16x32_bf16(A2.v, B1b.v, net1, 0, 0, 0);
        }
    }

    // ---------------------------------------------------------- fc_out -----
    const float wo0 = fc_out_W[cch];
    const float wo1 = fc_out_W[16 + cch];
    float acc[4];
    #pragma unroll
    for (int r = 0; r < 4; ++r)
        acc[r] = fmaxf(net0[r], 0.0f) * wo0 + fmaxf(net1[r], 0.0f) * wo1;
    #pragma unroll
    for (int m = 1; m < 16; m <<= 1) {
        #pragma unroll
        for (int r = 0; r < 4; ++r) acc[r] += __shfl_xor(acc[r], m, 64);
    }
    if (cch == 0) {
        const float ob = fc_out_b[0];
        #pragma unroll
        for (int r = 0; r < 4; ++r) out[tpt + q * 4 + r] = acc[r] + ob;
    }
}

extern "C" void kernel_launch(void* const* d_in, const int* in_sizes, int n_in,
                              void* d_out, int out_size, void* d_ws, size_t ws_size,
                              hipStream_t stream) {
    const float* p        = (const float*)d_in[0];
    // d_in[1] = z  -- unused by the reference
    const float* c        = (const float*)d_in[2];
    const float* Cmat     = (const float*)d_in[3];
    const float* fc_p_W   = (const float*)d_in[4];
    const float* fc_p_b   = (const float*)d_in[5];
    const float* W0       = (const float*)d_in[6];
    const float* b0       = (const float*)d_in[7];
    const float* W1       = (const float*)d_in[8];
    const float* b1       = (const float*)d_in[9];
    const float* fc_out_W = (const float*)d_in[10];
    const float* fc_out_b = (const float*)d_in[11];
    float* out = (float*)d_out;

    // 128 points/block, 512 threads/block -> 512 blocks (2 blocks/CU)
    decoder_fused_mfma<<<NPT / 128, 512, 0, stream>>>(p, c, Cmat, fc_p_W, fc_p_b,
                                                      W0, b0, W1, b1, fc_out_W, fc_out_b, out);
}